// Round 1
// baseline (650.644 us; speedup 1.0000x reference)
//
#include <hip/hip_runtime.h>

#define T_LEN   131072
#define NSTEPS  (T_LEN - 2)   // 131070 scan steps (measurements 2..T-1)
#define CHUNK   128
#define NCHUNK  1024          // ceil(NSTEPS/CHUNK)
#define CAP     4096          // max stored pre-convergence gains

// workspace byte offsets
#define OFF_STEADY 16                          // 2 floats: k1_st, k2_st
#define OFF_K1     32                          // CAP floats
#define OFF_K2     (OFF_K1 + CAP * 4)          // CAP floats
#define OFF_COMP   (OFF_K2 + CAP * 4)          // NCHUNK * 16 floats (M[4], u0[6], u1[6])
#define OFF_ZST    (OFF_COMP + NCHUNK * 16 * 4)// NCHUNK * 12 floats (x[6], y[6])
// total ws use = OFF_ZST + NCHUNK*12*4 ≈ 148 KB

// K1: serial scalar Riccati; store gains until convergence, then steady value.
__global__ void k_gains(const float* __restrict__ pnc, const float* __restrict__ mnc,
                        const float* __restrict__ cov, float* __restrict__ ws_f,
                        int* __restrict__ ws_i) {
    if (threadIdx.x != 0 || blockIdx.x != 0) return;
    float q = pnc[0];
    float r = mnc[0];
    float a = cov[0];          // P[0,0] block scalar
    float b = cov[6];          // P[0,6]
    float c = cov[6 * 12 + 6]; // P[6,6]
    float* k1a = ws_f + OFF_K1 / 4;
    float* k2a = ws_f + OFF_K2 / 4;
    float pk1 = -1e30f, pk2 = -1e30f;
    float k1 = 0.f, k2 = 0.f;
    int stable = 0;
    int s;
    for (s = 0; s < CAP; ++s) {
        // Pp = F P F^T + Q  (block-scalar form, mimics reference op order)
        float bp = 2.0f * a - b;          // Pp[0,6] = Pp[6,0]
        float t2 = 2.0f * b - c;
        float ap = 2.0f * bp - t2 + q;    // Pp[0,0]
        float cp = a;                     // Pp[6,6]
        float S  = ap + r;
        float invS = 1.0f / S;
        k1 = ap * invS;
        k2 = bp * invS;
        k1a[s] = k1;
        k2a[s] = k2;
        float om = 1.0f - k1;
        a = om * ap;
        b = om * bp;
        c = cp - k2 * bp;
        if (fabsf(k1 - pk1) <= 1e-7f * fabsf(k1) &&
            fabsf(k2 - pk2) <= 1e-7f * (fabsf(k2) + 1e-20f)) {
            if (++stable >= 16) { ++s; break; }
        } else {
            stable = 0;
        }
        pk1 = k1; pk2 = k2;
    }
    ws_i[0] = s;  // entries [0, s) of k1a/k2a valid; beyond: steady
    ws_f[OFF_STEADY / 4]     = k1;
    ws_f[OFF_STEADY / 4 + 1] = k2;
}

__device__ __forceinline__ void load_gains(int s, int sc, const float* k1a,
                                           const float* k2a, float k1s, float k2s,
                                           float& g1, float& g2) {
    int si = (s < sc) ? s : 0;       // keep load in-bounds; never read poisoned tail
    float a = k1a[si], b = k2a[si];
    g1 = (s < sc) ? a : k1s;
    g2 = (s < sc) ? b : k2s;
}

// K2: per-chunk affine composition. M (2x2) shared across coords; u per coord.
__global__ void k_chunk(const float* __restrict__ meas, const float* __restrict__ ws_f,
                        const int* __restrict__ ws_i, float* __restrict__ comp) {
    int c = blockIdx.x * blockDim.x + threadIdx.x;
    if (c >= NCHUNK) return;
    int sc = ws_i[0];
    float k1s = ws_f[OFF_STEADY / 4], k2s = ws_f[OFF_STEADY / 4 + 1];
    const float* k1a = ws_f + OFF_K1 / 4;
    const float* k2a = ws_f + OFF_K2 / 4;
    int s0 = c * CHUNK;
    int len = NSTEPS - s0; if (len > CHUNK) len = CHUNK;
    float m00 = 1.f, m01 = 0.f, m10 = 0.f, m11 = 1.f;
    float u0[6] = {0, 0, 0, 0, 0, 0}, u1[6] = {0, 0, 0, 0, 0, 0};
    for (int i = 0; i < len; ++i) {
        int s = s0 + i;
        float g1, g2;
        load_gains(s, sc, k1a, k2a, k1s, k2s, g1, g2);
        float om  = 1.0f - g1;
        float a00 = 2.0f * om, a01 = -om;
        float a10 = 1.0f - 2.0f * g2, a11 = g2;
        float n00 = a00 * m00 + a01 * m10;
        float n01 = a00 * m01 + a01 * m11;
        float n10 = a10 * m00 + a11 * m10;
        float n11 = a10 * m01 + a11 * m11;
        m00 = n00; m01 = n01; m10 = n10; m11 = n11;
        const float* mr = meas + (s + 2) * 6;
#pragma unroll
        for (int j = 0; j < 6; ++j) {
            float mj = mr[j];
            float v0 = a00 * u0[j] + a01 * u1[j] + g1 * mj;
            float v1 = a10 * u0[j] + a11 * u1[j] + g2 * mj;
            u0[j] = v0; u1[j] = v1;
        }
    }
    float* o = comp + c * 16;
    o[0] = m00; o[1] = m01; o[2] = m10; o[3] = m11;
#pragma unroll
    for (int j = 0; j < 6; ++j) { o[4 + j] = u0[j]; o[10 + j] = u1[j]; }
}

// K3: single-block Hillis-Steele inclusive scan over NCHUNK compositions,
// then emit per-chunk start states z_start(c) = S_{c-1}(z1).
__global__ void k_scan(const float* __restrict__ meas, const float* __restrict__ comp,
                       float* __restrict__ zst) {
    __shared__ float ld[NCHUNK * 16];  // 64 KB
    int tid = threadIdx.x;
    float S[16];
#pragma unroll
    for (int k = 0; k < 16; ++k) { S[k] = comp[tid * 16 + k]; ld[tid * 16 + k] = S[k]; }
    __syncthreads();
    for (int off = 1; off < NCHUNK; off <<= 1) {
        float P[16];
        bool act = (tid >= off);
        if (act) {
#pragma unroll
            for (int k = 0; k < 16; ++k) P[k] = ld[(tid - off) * 16 + k];
        }
        __syncthreads();
        if (act) {
            // S = S ∘ P  (P applied first): M = Ms*Mp, u = Ms*uP + uS
            float n00 = S[0] * P[0] + S[1] * P[2];
            float n01 = S[0] * P[1] + S[1] * P[3];
            float n10 = S[2] * P[0] + S[3] * P[2];
            float n11 = S[2] * P[1] + S[3] * P[3];
            float nu[12];
#pragma unroll
            for (int j = 0; j < 6; ++j) {
                nu[j]     = S[0] * P[4 + j] + S[1] * P[10 + j] + S[4 + j];
                nu[6 + j] = S[2] * P[4 + j] + S[3] * P[10 + j] + S[10 + j];
            }
            S[0] = n00; S[1] = n01; S[2] = n10; S[3] = n11;
#pragma unroll
            for (int k = 0; k < 12; ++k) S[4 + k] = nu[k];
#pragma unroll
            for (int k = 0; k < 16; ++k) ld[tid * 16 + k] = S[k];
        }
        __syncthreads();
    }
    float E[16];
    if (tid == 0) {
        E[0] = 1.f; E[1] = 0.f; E[2] = 0.f; E[3] = 1.f;
#pragma unroll
        for (int k = 4; k < 16; ++k) E[k] = 0.f;
    } else {
#pragma unroll
        for (int k = 0; k < 16; ++k) E[k] = ld[(tid - 1) * 16 + k];
    }
#pragma unroll
    for (int j = 0; j < 6; ++j) {
        float x1 = meas[6 + j];   // est row1 = [m1, m0]
        float y1 = meas[j];
        zst[tid * 12 + j]     = E[0] * x1 + E[1] * y1 + E[4 + j];
        zst[tid * 12 + 6 + j] = E[2] * x1 + E[3] * y1 + E[10 + j];
    }
}

// K4: replay each chunk sequentially from its start state with the reference's
// exact per-step arithmetic; emit est/pred/vel rows.
__global__ void k_emit(const float* __restrict__ meas, const float* __restrict__ ws_f,
                       const int* __restrict__ ws_i, const float* __restrict__ zst,
                       float* __restrict__ out) {
    int c = blockIdx.x * blockDim.x + threadIdx.x;
    if (c >= NCHUNK) return;
    int sc = ws_i[0];
    float k1s = ws_f[OFF_STEADY / 4], k2s = ws_f[OFF_STEADY / 4 + 1];
    const float* k1a = ws_f + OFF_K1 / 4;
    const float* k2a = ws_f + OFF_K2 / 4;
    float* est  = out;
    float* pred = out + T_LEN * 6;
    float* vel  = out + T_LEN * 12;
    if (c == 0) {
#pragma unroll
        for (int j = 0; j < 6; ++j) {
            float m0 = meas[j], m1 = meas[6 + j];
            est[j] = m0; est[6 + j] = m1;
            pred[j] = m0; pred[6 + j] = m1;
            vel[j] = m1 - m0;   // velocity row 0 (est row 1: x=m1, y=m0)
        }
    }
    float x[6], y[6];
#pragma unroll
    for (int j = 0; j < 6; ++j) { x[j] = zst[c * 12 + j]; y[j] = zst[c * 12 + 6 + j]; }
    int s0 = c * CHUNK;
    int len = NSTEPS - s0; if (len > CHUNK) len = CHUNK;
    for (int i = 0; i < len; ++i) {
        int s = s0 + i;
        float g1, g2;
        load_gains(s, sc, k1a, k2a, k1s, k2s, g1, g2);
        int t = s + 2;
        const float* mr = meas + t * 6;
        float* er = est + t * 6;
        float* pr = pred + t * 6;
        float* vr = vel + (s + 1) * 6;
        bool wv = (s + 1) < (T_LEN - 2);  // vel rows 1..T-3 come from s=0..T-4
#pragma unroll
        for (int j = 0; j < 6; ++j) {
            float vx  = x[j] - y[j];
            float p   = x[j] + vx;        // pred[:6] = est[:6] + v  (reference order)
            float inn = mr[j] - p;
            float xn  = p + g1 * inn;
            float yn  = x[j] + g2 * inn;
            er[j] = xn;
            pr[j] = p;
            if (wv) vr[j] = xn - yn;
            x[j] = xn; y[j] = yn;
        }
    }
}

extern "C" void kernel_launch(void* const* d_in, const int* in_sizes, int n_in,
                              void* d_out, int out_size, void* d_ws, size_t ws_size,
                              hipStream_t stream) {
    const float* meas = (const float*)d_in[0];  // (T,6)
    const float* pnc  = (const float*)d_in[1];  // (6,6)
    const float* mnc  = (const float*)d_in[2];  // (6,6)
    const float* cov  = (const float*)d_in[3];  // (12,12)
    float* ws_f = (float*)d_ws;
    int*   ws_i = (int*)d_ws;
    float* comp = ws_f + OFF_COMP / 4;
    float* zst  = ws_f + OFF_ZST / 4;
    float* out  = (float*)d_out;

    k_gains<<<1, 64, 0, stream>>>(pnc, mnc, cov, ws_f, ws_i);
    k_chunk<<<NCHUNK / 256, 256, 0, stream>>>(meas, ws_f, ws_i, comp);
    k_scan<<<1, NCHUNK, 0, stream>>>(meas, comp, zst);
    k_emit<<<NCHUNK / 256, 256, 0, stream>>>(meas, ws_f, ws_i, zst, out);
}

// Round 5
// 312.010 us; speedup vs baseline: 2.0853x; 2.0853x over previous
//
#include <hip/hip_runtime.h>

#define T_LEN   131072
#define NSTEPS  (T_LEN - 2)   // 131070 scan steps (measurements 2..T-1)
#define CHUNK   128
#define NCHUNK  1024
#define CAP     4096
#define ACT     32            // chunks per k_emit block (lanes 0..31 compute)
#define ITILE   16            // steps buffered in LDS before flush
#define LDSTR   (ACT + 1)     // LDS pad stride

// workspace byte offsets
#define OFF_STEADY 16
#define OFF_K1     32
#define OFF_K2     (OFF_K1 + CAP * 4)
#define OFF_COMP   (OFF_K2 + CAP * 4)
#define OFF_ZST    (OFF_COMP + NCHUNK * 16 * 4)
#define OFF_MT     (OFF_ZST + NCHUNK * 12 * 4)
#define MT_FLOATS  (CHUNK * 6 * NCHUNK)
#define WS_NEED    ((size_t)OFF_MT + (size_t)MT_FLOATS * 4)

// K1 (block 0): serial scalar Riccati. Blocks >0: transpose meas -> mT[i][j][c].
__global__ __launch_bounds__(256) void k_gains_xpose(
    const float* __restrict__ pnc, const float* __restrict__ mnc,
    const float* __restrict__ cov, const float* __restrict__ meas,
    float* __restrict__ ws_f, int* __restrict__ ws_i, int do_xpose) {
    if (blockIdx.x == 0) {
        if (threadIdx.x != 0) return;
        float q = pnc[0];
        float r = mnc[0];
        float a = cov[0];
        float b = cov[6];
        float c = cov[6 * 12 + 6];
        float* k1a = ws_f + OFF_K1 / 4;
        float* k2a = ws_f + OFF_K2 / 4;
        float pk1 = -1e30f, pk2 = -1e30f;
        float k1 = 0.f, k2 = 0.f;
        int stable = 0;
        int s;
        for (s = 0; s < CAP; ++s) {
            float bp = 2.0f * a - b;
            float t2 = 2.0f * b - c;
            float ap = 2.0f * bp - t2 + q;
            float cp = a;
            float S  = ap + r;
            float invS = 1.0f / S;
            k1 = ap * invS;
            k2 = bp * invS;
            k1a[s] = k1;
            k2a[s] = k2;
            float om = 1.0f - k1;
            a = om * ap;
            b = om * bp;
            c = cp - k2 * bp;
            // 5e-7 rel (~4 ULP) so a last-ULP limit cycle still counts as converged
            if (fabsf(k1 - pk1) <= 5e-7f * fabsf(k1) &&
                fabsf(k2 - pk2) <= 5e-7f * (fabsf(k2) + 1e-20f)) {
                if (++stable >= 8) { ++s; break; }
            } else {
                stable = 0;
            }
            pk1 = k1; pk2 = k2;
        }
        ws_i[0] = s;
        ws_f[OFF_STEADY / 4]     = k1;
        ws_f[OFF_STEADY / 4 + 1] = k2;
        return;
    }
    if (!do_xpose) return;
    int w = (blockIdx.x - 1) * 256 + threadIdx.x;   // 0 .. MT_FLOATS-1
    if (w >= MT_FLOATS) return;
    int c = w & (NCHUNK - 1);
    int f = w >> 10;             // i*6 + j
    int i = f / 6, j = f - 6 * i;
    int s = c * CHUNK + i;
    float v = (s < NSTEPS) ? meas[(s + 2) * 6 + j] : 0.f;
    ws_f[OFF_MT / 4 + w] = v;
}

__device__ __forceinline__ void load_gains(int s, int sc, const float* k1a,
                                           const float* k2a, float k1s, float k2s,
                                           float& g1, float& g2) {
    int si = (s < sc) ? s : 0;
    float a = k1a[si], b = k2a[si];
    g1 = (s < sc) ? a : k1s;
    g2 = (s < sc) ? b : k2s;
}

// K2: per-chunk affine composition (identical arithmetic; coalesced mT loads).
__global__ __launch_bounds__(64) void k_chunk(
    const float* __restrict__ meas, const float* __restrict__ ws_f,
    const int* __restrict__ ws_i, float* __restrict__ comp, int use_mt) {
    int c = blockIdx.x * 64 + threadIdx.x;
    if (c >= NCHUNK) return;
    int sc = ws_i[0];
    float k1s = ws_f[OFF_STEADY / 4], k2s = ws_f[OFF_STEADY / 4 + 1];
    const float* k1a = ws_f + OFF_K1 / 4;
    const float* k2a = ws_f + OFF_K2 / 4;
    const float* mT  = ws_f + OFF_MT / 4;
    int s0 = c * CHUNK;
    float m00 = 1.f, m01 = 0.f, m10 = 0.f, m11 = 1.f;
    float u0[6] = {0, 0, 0, 0, 0, 0}, u1[6] = {0, 0, 0, 0, 0, 0};
    for (int i = 0; i < CHUNK; ++i) {
        int s = s0 + i;
        if (s >= NSTEPS) break;
        float g1, g2;
        load_gains(s, sc, k1a, k2a, k1s, k2s, g1, g2);
        float om  = 1.0f - g1;
        float a00 = 2.0f * om, a01 = -om;
        float a10 = 1.0f - 2.0f * g2, a11 = g2;
        float n00 = a00 * m00 + a01 * m10;
        float n01 = a00 * m01 + a01 * m11;
        float n10 = a10 * m00 + a11 * m10;
        float n11 = a10 * m01 + a11 * m11;
        m00 = n00; m01 = n01; m10 = n10; m11 = n11;
        const float* mr = meas + (s + 2) * 6;
#pragma unroll
        for (int j = 0; j < 6; ++j) {
            float mj = use_mt ? mT[(i * 6 + j) * NCHUNK + c] : mr[j];
            float v0 = a00 * u0[j] + a01 * u1[j] + g1 * mj;
            float v1 = a10 * u0[j] + a11 * u1[j] + g2 * mj;
            u0[j] = v0; u1[j] = v1;
        }
    }
    float* o = comp + c * 16;
    o[0] = m00; o[1] = m01; o[2] = m10; o[3] = m11;
#pragma unroll
    for (int j = 0; j < 6; ++j) { o[4 + j] = u0[j]; o[10 + j] = u1[j]; }
}

// K3: single-block Hillis-Steele scan + per-chunk start states.
__global__ __launch_bounds__(1024) void k_scan(
    const float* __restrict__ meas, const float* __restrict__ comp,
    float* __restrict__ zst) {
    __shared__ float ld[NCHUNK * 16];  // 64 KB
    int tid = threadIdx.x;
    float S[16];
#pragma unroll
    for (int k = 0; k < 16; ++k) { S[k] = comp[tid * 16 + k]; ld[tid * 16 + k] = S[k]; }
    __syncthreads();
    for (int off = 1; off < NCHUNK; off <<= 1) {
        float P[16];
        bool act = (tid >= off);
        if (act) {
#pragma unroll
            for (int k = 0; k < 16; ++k) P[k] = ld[(tid - off) * 16 + k];
        }
        __syncthreads();
        if (act) {
            float n00 = S[0] * P[0] + S[1] * P[2];
            float n01 = S[0] * P[1] + S[1] * P[3];
            float n10 = S[2] * P[0] + S[3] * P[2];
            float n11 = S[2] * P[1] + S[3] * P[3];
            float nu[12];
#pragma unroll
            for (int j = 0; j < 6; ++j) {
                nu[j]     = S[0] * P[4 + j] + S[1] * P[10 + j] + S[4 + j];
                nu[6 + j] = S[2] * P[4 + j] + S[3] * P[10 + j] + S[10 + j];
            }
            S[0] = n00; S[1] = n01; S[2] = n10; S[3] = n11;
#pragma unroll
            for (int k = 0; k < 12; ++k) S[4 + k] = nu[k];
#pragma unroll
            for (int k = 0; k < 16; ++k) ld[tid * 16 + k] = S[k];
        }
        __syncthreads();
    }
    float E[16];
    if (tid == 0) {
        E[0] = 1.f; E[1] = 0.f; E[2] = 0.f; E[3] = 1.f;
#pragma unroll
        for (int k = 4; k < 16; ++k) E[k] = 0.f;
    } else {
#pragma unroll
        for (int k = 0; k < 16; ++k) E[k] = ld[(tid - 1) * 16 + k];
    }
#pragma unroll
    for (int j = 0; j < 6; ++j) {
        float x1 = meas[6 + j];
        float y1 = meas[j];
        zst[tid * 12 + j]     = E[0] * x1 + E[1] * y1 + E[4 + j];
        zst[tid * 12 + 6 + j] = E[2] * x1 + E[3] * y1 + E[10 + j];
    }
}

// K4 (fast path): replay chunks; outputs staged in LDS, flushed as contiguous
// float2 runs (384 B per chunk per array) for coalesced stores.
__global__ __launch_bounds__(64) void k_emit_tiled(
    const float* __restrict__ meas, const float* __restrict__ ws_f,
    const int* __restrict__ ws_i, const float* __restrict__ zst,
    float* __restrict__ out) {
    __shared__ float tE[ITILE * 6 * LDSTR];
    __shared__ float tP[ITILE * 6 * LDSTR];
    __shared__ float tV[ITILE * 6 * LDSTR];
    int lane = threadIdx.x;
    int b = blockIdx.x;
    int c = b * ACT + lane;
    bool active = lane < ACT;
    float* est  = out;
    float* pred = out + T_LEN * 6;
    float* vel  = out + T_LEN * 12;
    if (b == 0 && lane == 0) {
#pragma unroll
        for (int j = 0; j < 6; ++j) {
            float m0 = meas[j], m1 = meas[6 + j];
            est[j] = m0; est[6 + j] = m1;
            pred[j] = m0; pred[6 + j] = m1;
            vel[j] = m1 - m0;
        }
    }
    int sc = ws_i[0];
    float k1s = ws_f[OFF_STEADY / 4], k2s = ws_f[OFF_STEADY / 4 + 1];
    const float* k1a = ws_f + OFF_K1 / 4;
    const float* k2a = ws_f + OFF_K2 / 4;
    const float* mT  = ws_f + OFF_MT / 4;
    float x[6], y[6];
    if (active) {
#pragma unroll
        for (int j = 0; j < 6; ++j) { x[j] = zst[c * 12 + j]; y[j] = zst[c * 12 + 6 + j]; }
    }
    int s0 = c * CHUNK;
    for (int ph = 0; ph < CHUNK / ITILE; ++ph) {
        int ibase = ph * ITILE;
        if (active) {
            for (int ii = 0; ii < ITILE; ++ii) {
                int i = ibase + ii;
                int s = s0 + i;
                if (s < NSTEPS) {
                    float g1, g2;
                    load_gains(s, sc, k1a, k2a, k1s, k2s, g1, g2);
#pragma unroll
                    for (int j = 0; j < 6; ++j) {
                        float mj  = mT[(i * 6 + j) * NCHUNK + c];
                        float vx  = x[j] - y[j];
                        float p   = x[j] + vx;
                        float inn = mj - p;
                        float xn  = p + g1 * inn;
                        float yn  = x[j] + g2 * inn;
                        int idx = (ii * 6 + j) * LDSTR + lane;
                        tE[idx] = xn; tP[idx] = p; tV[idx] = xn - yn;
                        x[j] = xn; y[j] = yn;
                    }
                }
            }
        }
        __syncthreads();
        // flush: ACT chunks * ITILE rows * 6 floats = 3072 floats = 1536 float2 per array
#pragma unroll
        for (int t = 0; t < (ACT * ITILE * 3) / 64; ++t) {   // 24 iters
            int w = t * 64 + lane;              // 0..1535
            int cc = w / 48, q2 = w - cc * 48;  // 48 float2 per chunk-tile
            int f = q2 * 2;                     // even float index in tile row-major
            int ii = f / 6, jj = f - ii * 6;    // jj in {0,2,4}
            int cg = b * ACT + cc;
            int srow = cg * CHUNK + ibase + ii;
            int lidx = (ii * 6 + jj) * LDSTR + cc;
            float2 vE = make_float2(tE[lidx], tE[lidx + LDSTR]);
            float2 vP = make_float2(tP[lidx], tP[lidx + LDSTR]);
            float2 vV = make_float2(tV[lidx], tV[lidx + LDSTR]);
            if (srow < NSTEPS) {
                *reinterpret_cast<float2*>(est  + (srow + 2) * 6 + jj) = vE;
                *reinterpret_cast<float2*>(pred + (srow + 2) * 6 + jj) = vP;
            }
            if (srow < NSTEPS - 1) {
                *reinterpret_cast<float2*>(vel + (srow + 1) * 6 + jj) = vV;
            }
        }
        __syncthreads();
    }
}

// K4 (fallback, round-1 style direct stores) — used only if ws is too small.
__global__ void k_emit_direct(const float* __restrict__ meas, const float* __restrict__ ws_f,
                              const int* __restrict__ ws_i, const float* __restrict__ zst,
                              float* __restrict__ out) {
    int c = blockIdx.x * blockDim.x + threadIdx.x;
    if (c >= NCHUNK) return;
    int sc = ws_i[0];
    float k1s = ws_f[OFF_STEADY / 4], k2s = ws_f[OFF_STEADY / 4 + 1];
    const float* k1a = ws_f + OFF_K1 / 4;
    const float* k2a = ws_f + OFF_K2 / 4;
    float* est  = out;
    float* pred = out + T_LEN * 6;
    float* vel  = out + T_LEN * 12;
    if (c == 0) {
#pragma unroll
        for (int j = 0; j < 6; ++j) {
            float m0 = meas[j], m1 = meas[6 + j];
            est[j] = m0; est[6 + j] = m1;
            pred[j] = m0; pred[6 + j] = m1;
            vel[j] = m1 - m0;
        }
    }
    float x[6], y[6];
#pragma unroll
    for (int j = 0; j < 6; ++j) { x[j] = zst[c * 12 + j]; y[j] = zst[c * 12 + 6 + j]; }
    int s0 = c * CHUNK;
    int len = NSTEPS - s0; if (len > CHUNK) len = CHUNK;
    for (int i = 0; i < len; ++i) {
        int s = s0 + i;
        float g1, g2;
        load_gains(s, sc, k1a, k2a, k1s, k2s, g1, g2);
        int t = s + 2;
        const float* mr = meas + t * 6;
        float* er = est + t * 6;
        float* pr = pred + t * 6;
        float* vr = vel + (s + 1) * 6;
        bool wv = (s + 1) < (T_LEN - 2);
#pragma unroll
        for (int j = 0; j < 6; ++j) {
            float vx  = x[j] - y[j];
            float p   = x[j] + vx;
            float inn = mr[j] - p;
            float xn  = p + g1 * inn;
            float yn  = x[j] + g2 * inn;
            er[j] = xn;
            pr[j] = p;
            if (wv) vr[j] = xn - yn;
            x[j] = xn; y[j] = yn;
        }
    }
}

extern "C" void kernel_launch(void* const* d_in, const int* in_sizes, int n_in,
                              void* d_out, int out_size, void* d_ws, size_t ws_size,
                              hipStream_t stream) {
    const float* meas = (const float*)d_in[0];
    const float* pnc  = (const float*)d_in[1];
    const float* mnc  = (const float*)d_in[2];
    const float* cov  = (const float*)d_in[3];
    float* ws_f = (float*)d_ws;
    int*   ws_i = (int*)d_ws;
    float* comp = ws_f + OFF_COMP / 4;
    float* zst  = ws_f + OFF_ZST / 4;
    float* out  = (float*)d_out;

    bool big = ws_size >= WS_NEED;
    if (big) {
        k_gains_xpose<<<1 + MT_FLOATS / 256, 256, 0, stream>>>(pnc, mnc, cov, meas, ws_f, ws_i, 1);
        k_chunk<<<NCHUNK / 64, 64, 0, stream>>>(meas, ws_f, ws_i, comp, 1);
        k_scan<<<1, NCHUNK, 0, stream>>>(meas, comp, zst);
        k_emit_tiled<<<NCHUNK / ACT, 64, 0, stream>>>(meas, ws_f, ws_i, zst, out);
    } else {
        k_gains_xpose<<<1, 256, 0, stream>>>(pnc, mnc, cov, meas, ws_f, ws_i, 0);
        k_chunk<<<NCHUNK / 64, 64, 0, stream>>>(meas, ws_f, ws_i, comp, 0);
        k_scan<<<1, NCHUNK, 0, stream>>>(meas, comp, zst);
        k_emit_direct<<<NCHUNK / 256, 256, 0, stream>>>(meas, ws_f, ws_i, zst, out);
    }
}

// Round 8
// 138.334 us; speedup vs baseline: 4.7034x; 2.2555x over previous
//
#include <hip/hip_runtime.h>

#define T_LEN   131072
#define NSTEPS  (T_LEN - 2)      // 131070 scan steps (measurements 2..T-1)
#define CHUNK   16
#define NCHUNK  8192             // 8192*16 = 131072 >= NSTEPS
#define NCJ     (NCHUNK * 6)     // chunk x coord lanes = 49152
#define CAP     512              // max stored pre-convergence gains
#define SCAN_T  1024
#define PERT    (NCHUNK / SCAN_T) // 8 chunks serial per scan thread

// workspace byte offsets (16B aligned where vector-loaded)
#define OFF_STEADY 16
#define OFF_K1     32
#define OFF_K2     (OFF_K1 + CAP * 4)                 // 2080
#define OFF_COMP   (OFF_K2 + CAP * 4)                 // 4128 (16B aligned)
#define OFF_ZST    (OFF_COMP + NCHUNK * 16 * 4)       // + 512KB
#define OFF_MT     (OFF_ZST + NCHUNK * 12 * 4)        // + 384KB
#define MT_FLOATS  (CHUNK * 6 * NCHUNK)               // 786432 (3MB)
#define WS_NEED    ((size_t)OFF_MT + (size_t)MT_FLOATS * 4)   // ~3.9MB
#define WS_MIN     ((size_t)OFF_MT)                   // fallback (no mT) ~0.9MB

// K1 (block 0): serial scalar Riccati. Blocks >0: transpose meas -> mT[i][j][c].
__global__ __launch_bounds__(256) void k_gains_xpose(
    const float* __restrict__ pnc, const float* __restrict__ mnc,
    const float* __restrict__ cov, const float* __restrict__ meas,
    float* __restrict__ ws_f, int* __restrict__ ws_i, int do_xpose) {
    if (blockIdx.x == 0) {
        if (threadIdx.x != 0) return;
        float q = pnc[0];
        float r = mnc[0];
        float a = cov[0];
        float b = cov[6];
        float c = cov[6 * 12 + 6];
        float* k1a = ws_f + OFF_K1 / 4;
        float* k2a = ws_f + OFF_K2 / 4;
        float pk1 = -1e30f, pk2 = -1e30f;
        float k1 = 0.f, k2 = 0.f;
        int stable = 0;
        int s;
        for (s = 0; s < CAP; ++s) {
            float bp = 2.0f * a - b;
            float t2 = 2.0f * b - c;
            float ap = 2.0f * bp - t2 + q;
            float cp = a;
            float S  = ap + r;
            float invS = 1.0f / S;
            k1 = ap * invS;
            k2 = bp * invS;
            k1a[s] = k1;
            k2a[s] = k2;
            float om = 1.0f - k1;
            a = om * ap;
            b = om * bp;
            c = cp - k2 * bp;
            if (fabsf(k1 - pk1) <= 5e-7f * fabsf(k1) &&
                fabsf(k2 - pk2) <= 5e-7f * (fabsf(k2) + 1e-20f)) {
                if (++stable >= 8) { ++s; break; }
            } else {
                stable = 0;
            }
            pk1 = k1; pk2 = k2;
        }
        ws_i[0] = s;
        ws_f[OFF_STEADY / 4]     = k1;
        ws_f[OFF_STEADY / 4 + 1] = k2;
        return;
    }
    if (!do_xpose) return;
    int w = (blockIdx.x - 1) * 256 + threadIdx.x;   // 0 .. MT_FLOATS-1
    if (w >= MT_FLOATS) return;
    int c = w & (NCHUNK - 1);
    int f = w >> 13;             // i*6 + j, 0..95
    int i = f / 6, j = f - 6 * i;
    int s = c * CHUNK + i;
    float v = (s < NSTEPS) ? meas[(s + 2) * 6 + j] : 0.f;
    ws_f[OFF_MT / 4 + w] = v;
}

__device__ __forceinline__ void load_gains(int s, int sc, const float* k1a,
                                           const float* k2a, float k1s, float k2s,
                                           float& g1, float& g2) {
    int si = (s < sc) ? s : 0;
    float a = k1a[si], b = k2a[si];
    g1 = (s < sc) ? a : k1s;
    g2 = (s < sc) ? b : k2s;
}

// K2: per-(chunk,coord) affine composition over 16 steps.
// M (2x2, gains-only) computed redundantly per lane; j==0 lane stores it.
__global__ __launch_bounds__(256) void k_chunk(
    const float* __restrict__ meas, const float* __restrict__ ws_f,
    const int* __restrict__ ws_i, float* __restrict__ comp, int use_mt) {
    int g = blockIdx.x * 256 + threadIdx.x;
    if (g >= NCJ) return;
    int j = g >> 13;             // coord 0..5
    int c = g & (NCHUNK - 1);    // chunk
    int sc = ws_i[0];
    float k1s = ws_f[OFF_STEADY / 4], k2s = ws_f[OFF_STEADY / 4 + 1];
    const float* k1a = ws_f + OFF_K1 / 4;
    const float* k2a = ws_f + OFF_K2 / 4;
    const float* mT  = ws_f + OFF_MT / 4;
    int s0 = c * CHUNK;
    float m00 = 1.f, m01 = 0.f, m10 = 0.f, m11 = 1.f;
    float u0 = 0.f, u1 = 0.f;
#pragma unroll
    for (int i = 0; i < CHUNK; ++i) {
        int s = s0 + i;
        if (s < NSTEPS) {
            float g1, g2;
            load_gains(s, sc, k1a, k2a, k1s, k2s, g1, g2);
            float om  = 1.0f - g1;
            float a00 = 2.0f * om, a01 = -om;
            float a10 = 1.0f - 2.0f * g2, a11 = g2;
            float n00 = a00 * m00 + a01 * m10;
            float n01 = a00 * m01 + a01 * m11;
            float n10 = a10 * m00 + a11 * m10;
            float n11 = a10 * m01 + a11 * m11;
            m00 = n00; m01 = n01; m10 = n10; m11 = n11;
            float mj = use_mt ? mT[(i * 6 + j) * NCHUNK + c]
                              : meas[(s + 2) * 6 + j];
            float v0 = a00 * u0 + a01 * u1 + g1 * mj;
            float v1 = a10 * u0 + a11 * u1 + g2 * mj;
            u0 = v0; u1 = v1;
        }
    }
    comp[c * 16 + 4 + j]  = u0;
    comp[c * 16 + 10 + j] = u1;
    if (j == 0) {
        comp[c * 16 + 0] = m00; comp[c * 16 + 1] = m01;
        comp[c * 16 + 2] = m10; comp[c * 16 + 3] = m11;
    }
}

__device__ __forceinline__ void compose(const float* L, const float* E, float* D) {
    // D = L ∘ E  (E applied first): M = ML*ME, u = ML*uE + uL
    float n00 = L[0] * E[0] + L[1] * E[2];
    float n01 = L[0] * E[1] + L[1] * E[3];
    float n10 = L[2] * E[0] + L[3] * E[2];
    float n11 = L[2] * E[1] + L[3] * E[3];
#pragma unroll
    for (int j = 0; j < 6; ++j) {
        float e0 = E[4 + j], e1 = E[10 + j];
        D[4 + j]  = L[0] * e0 + L[1] * e1 + L[4 + j];
        D[10 + j] = L[2] * e0 + L[3] * e1 + L[10 + j];
    }
    D[0] = n00; D[1] = n01; D[2] = n10; D[3] = n11;
}

// K3: scan over NCHUNK compositions (PERT serial per thread + LDS Hillis-Steele),
// then forward-walk to emit per-chunk start states (transposed layout).
__global__ __launch_bounds__(SCAN_T) void k_scan(
    const float* __restrict__ meas, const float* __restrict__ comp,
    float* __restrict__ zst) {
    __shared__ float ld[SCAN_T * 16];  // 64 KB
    int t = threadIdx.x;
    float S[16], C[16], P[16];
#pragma unroll
    for (int k = 0; k < 16; ++k) S[k] = comp[(t * PERT) * 16 + k];
    for (int kk = 1; kk < PERT; ++kk) {
#pragma unroll
        for (int k = 0; k < 16; ++k) C[k] = comp[(t * PERT + kk) * 16 + k];
        float D[16];
        compose(C, S, D);
#pragma unroll
        for (int k = 0; k < 16; ++k) S[k] = D[k];
    }
#pragma unroll
    for (int k = 0; k < 16; ++k) ld[t * 16 + k] = S[k];
    __syncthreads();
    for (int off = 1; off < SCAN_T; off <<= 1) {
        bool act = (t >= off);
        if (act) {
#pragma unroll
            for (int k = 0; k < 16; ++k) P[k] = ld[(t - off) * 16 + k];
        }
        __syncthreads();
        if (act) {
            float D[16];
            compose(S, P, D);
#pragma unroll
            for (int k = 0; k < 16; ++k) { S[k] = D[k]; ld[t * 16 + k] = S[k]; }
        }
        __syncthreads();
    }
    float E[16];
    if (t == 0) {
        E[0] = 1.f; E[1] = 0.f; E[2] = 0.f; E[3] = 1.f;
#pragma unroll
        for (int k = 4; k < 16; ++k) E[k] = 0.f;
    } else {
#pragma unroll
        for (int k = 0; k < 16; ++k) E[k] = ld[(t - 1) * 16 + k];
    }
    // z1 per coord: x1 = meas[6+j], y1 = meas[j]
    for (int kk = 0; kk < PERT; ++kk) {
        int c = t * PERT + kk;
#pragma unroll
        for (int j = 0; j < 6; ++j) {
            float x1 = meas[6 + j];
            float y1 = meas[j];
            zst[(2 * j) * NCHUNK + c]     = E[0] * x1 + E[1] * y1 + E[4 + j];
            zst[(2 * j + 1) * NCHUNK + c] = E[2] * x1 + E[3] * y1 + E[10 + j];
        }
        if (kk < PERT - 1) {
#pragma unroll
            for (int k = 0; k < 16; ++k) C[k] = comp[c * 16 + k];
            float D[16];
            compose(C, E, D);
#pragma unroll
            for (int k = 0; k < 16; ++k) E[k] = D[k];
        }
    }
}

// K4: per-(chunk,coord) replay, 16 steps, reference-exact arithmetic.
__global__ __launch_bounds__(256) void k_emit(
    const float* __restrict__ meas, const float* __restrict__ ws_f,
    const int* __restrict__ ws_i, const float* __restrict__ zst,
    float* __restrict__ out, int use_mt) {
    int g = blockIdx.x * 256 + threadIdx.x;
    if (g >= NCJ) return;
    int j = g >> 13;
    int c = g & (NCHUNK - 1);
    float* est  = out;
    float* pred = out + T_LEN * 6;
    float* vel  = out + T_LEN * 12;
    if (c == 0) {
        float m0 = meas[j], m1 = meas[6 + j];
        est[j] = m0; est[6 + j] = m1;
        pred[j] = m0; pred[6 + j] = m1;
        vel[j] = m1 - m0;
    }
    int sc = ws_i[0];
    float k1s = ws_f[OFF_STEADY / 4], k2s = ws_f[OFF_STEADY / 4 + 1];
    const float* k1a = ws_f + OFF_K1 / 4;
    const float* k2a = ws_f + OFF_K2 / 4;
    const float* mT  = ws_f + OFF_MT / 4;
    float x = zst[(2 * j) * NCHUNK + c];
    float y = zst[(2 * j + 1) * NCHUNK + c];
    int s0 = c * CHUNK;
#pragma unroll
    for (int i = 0; i < CHUNK; ++i) {
        int s = s0 + i;
        if (s < NSTEPS) {
            float g1, g2;
            load_gains(s, sc, k1a, k2a, k1s, k2s, g1, g2);
            float mj = use_mt ? mT[(i * 6 + j) * NCHUNK + c]
                              : meas[(s + 2) * 6 + j];
            float vx  = x - y;
            float p   = x + vx;
            float inn = mj - p;
            float xn  = p + g1 * inn;
            float yn  = x + g2 * inn;
            est[(s + 2) * 6 + j]  = xn;
            pred[(s + 2) * 6 + j] = p;
            if (s < NSTEPS - 1) vel[(s + 1) * 6 + j] = xn - yn;
            x = xn; y = yn;
        }
    }
}

extern "C" void kernel_launch(void* const* d_in, const int* in_sizes, int n_in,
                              void* d_out, int out_size, void* d_ws, size_t ws_size,
                              hipStream_t stream) {
    const float* meas = (const float*)d_in[0];
    const float* pnc  = (const float*)d_in[1];
    const float* mnc  = (const float*)d_in[2];
    const float* cov  = (const float*)d_in[3];
    float* ws_f = (float*)d_ws;
    int*   ws_i = (int*)d_ws;
    float* comp = ws_f + OFF_COMP / 4;
    float* zst  = ws_f + OFF_ZST / 4;
    float* out  = (float*)d_out;

    int use_mt = (ws_size >= WS_NEED) ? 1 : 0;
    int xb = use_mt ? 1 + MT_FLOATS / 256 : 1;
    k_gains_xpose<<<xb, 256, 0, stream>>>(pnc, mnc, cov, meas, ws_f, ws_i, use_mt);
    k_chunk<<<NCJ / 256, 256, 0, stream>>>(meas, ws_f, ws_i, comp, use_mt);
    k_scan<<<1, SCAN_T, 0, stream>>>(meas, comp, zst);
    k_emit<<<NCJ / 256, 256, 0, stream>>>(meas, ws_f, ws_i, zst, out, use_mt);
}

// Round 9
// 93.230 us; speedup vs baseline: 6.9789x; 1.4838x over previous
//
#include <hip/hip_runtime.h>

#define T_LEN   131072
#define NSTEPS  (T_LEN - 2)      // 131070 scan steps (measurements 2..T-1)
#define CHUNK   16
#define NCHUNK  8192             // 8192*16 = 131072 >= NSTEPS
#define NCJ     (NCHUNK * 6)     // 49152 (chunk,coord) lanes
#define CAP     512
#define CPB     128              // chunks per scan block
#define NBLK    (NCHUNK / CPB)   // 64
#define K2T     (CPB * 6)        // 768 threads

// workspace byte offsets (16B aligned)
#define OFF_STEADY 16
#define OFF_K1     32
#define OFF_K2     (OFF_K1 + CAP * 4)            // 2080
#define OFF_LP     (OFF_K2 + CAP * 4)            // 4128; NCHUNK*16 floats (512KB)
#define OFF_BT     (OFF_LP + NCHUNK * 16 * 4)    // NBLK*16 floats
#define OFF_BI     (OFF_BT + NBLK * 16 * 4)
#define OFF_MT     (OFF_BI + NBLK * 16 * 4)
#define MT_FLOATS  (CHUNK * 6 * NCHUNK)          // 786432 (3MB)
#define WS_NEED    ((size_t)OFF_MT + (size_t)MT_FLOATS * 4)   // ~3.6MB

// K1 (block 0): serial scalar Riccati. Blocks >0: transpose meas -> mT[i][j][c].
__global__ __launch_bounds__(256) void k_gains_xpose(
    const float* __restrict__ pnc, const float* __restrict__ mnc,
    const float* __restrict__ cov, const float* __restrict__ meas,
    float* __restrict__ ws_f, int* __restrict__ ws_i, int do_xpose) {
    if (blockIdx.x == 0) {
        if (threadIdx.x != 0) return;
        float q = pnc[0];
        float r = mnc[0];
        float a = cov[0];
        float b = cov[6];
        float c = cov[6 * 12 + 6];
        float* k1a = ws_f + OFF_K1 / 4;
        float* k2a = ws_f + OFF_K2 / 4;
        float pk1 = -1e30f, pk2 = -1e30f;
        float k1 = 0.f, k2 = 0.f;
        int stable = 0;
        int s;
        for (s = 0; s < CAP; ++s) {
            float bp = 2.0f * a - b;
            float t2 = 2.0f * b - c;
            float ap = 2.0f * bp - t2 + q;
            float cp = a;
            float S  = ap + r;
            float invS = 1.0f / S;
            k1 = ap * invS;
            k2 = bp * invS;
            k1a[s] = k1;
            k2a[s] = k2;
            float om = 1.0f - k1;
            a = om * ap;
            b = om * bp;
            c = cp - k2 * bp;
            if (fabsf(k1 - pk1) <= 5e-7f * fabsf(k1) &&
                fabsf(k2 - pk2) <= 5e-7f * (fabsf(k2) + 1e-20f)) {
                if (++stable >= 8) { ++s; break; }
            } else {
                stable = 0;
            }
            pk1 = k1; pk2 = k2;
        }
        ws_i[0] = s;
        ws_f[OFF_STEADY / 4]     = k1;
        ws_f[OFF_STEADY / 4 + 1] = k2;
        return;
    }
    if (!do_xpose) return;
    int w = (blockIdx.x - 1) * 256 + threadIdx.x;   // 0 .. MT_FLOATS-1
    if (w >= MT_FLOATS) return;
    int c = w & (NCHUNK - 1);
    int f = w >> 13;             // i*6 + j, 0..95
    int i = f / 6, j = f - 6 * i;
    int s = c * CHUNK + i;
    float v = (s < NSTEPS) ? meas[(s + 2) * 6 + j] : 0.f;
    ws_f[OFF_MT / 4 + w] = v;
}

__device__ __forceinline__ void load_gains(int s, int sc, const float* k1a,
                                           const float* k2a, float k1s, float k2s,
                                           float& g1, float& g2) {
    int si = (s < sc) ? s : 0;
    float a = k1a[si], b = k2a[si];
    g1 = (s < sc) ? a : k1s;
    g2 = (s < sc) ? b : k2s;
}

// K2: per-(chunk,coord) composition + intra-block Hillis-Steele local scan.
// Writes per-chunk local prefixes (lp) and per-block totals (btot).
__global__ __launch_bounds__(K2T) void k_chunk_scan(
    const float* __restrict__ meas, const float* __restrict__ ws_f,
    const int* __restrict__ ws_i, float* __restrict__ lp,
    float* __restrict__ btot, int use_mt) {
    __shared__ float lm[CPB][5];    // 2x2 M per chunk (pad 5 vs bank conflicts)
    __shared__ float lu[CPB][13];   // u0[6],u1[6] per chunk (pad 13)
    int tid = threadIdx.x;
    int cl = tid & (CPB - 1);
    int j  = tid >> 7;              // 0..5
    int b  = blockIdx.x;
    int c  = b * CPB + cl;
    int sc = ws_i[0];
    float k1s = ws_f[OFF_STEADY / 4], k2s = ws_f[OFF_STEADY / 4 + 1];
    const float* k1a = ws_f + OFF_K1 / 4;
    const float* k2a = ws_f + OFF_K2 / 4;
    const float* mT  = ws_f + OFF_MT / 4;
    // phase 1: chunk composition (M redundant per j; u per (chunk, coord))
    int s0 = c * CHUNK;
    float m00 = 1.f, m01 = 0.f, m10 = 0.f, m11 = 1.f;
    float u0 = 0.f, u1 = 0.f;
#pragma unroll
    for (int i = 0; i < CHUNK; ++i) {
        int s = s0 + i;
        if (s < NSTEPS) {
            float g1, g2;
            load_gains(s, sc, k1a, k2a, k1s, k2s, g1, g2);
            float om  = 1.0f - g1;
            float a00 = 2.0f * om, a01 = -om;
            float a10 = 1.0f - 2.0f * g2, a11 = g2;
            float n00 = a00 * m00 + a01 * m10;
            float n01 = a00 * m01 + a01 * m11;
            float n10 = a10 * m00 + a11 * m10;
            float n11 = a10 * m01 + a11 * m11;
            m00 = n00; m01 = n01; m10 = n10; m11 = n11;
            float mj = use_mt ? mT[(i * 6 + j) * NCHUNK + c]
                              : meas[(s + 2) * 6 + j];
            float v0 = a00 * u0 + a01 * u1 + g1 * mj;
            float v1 = a10 * u0 + a11 * u1 + g2 * mj;
            u0 = v0; u1 = v1;
        }
    }
    if (j == 0) { lm[cl][0] = m00; lm[cl][1] = m01; lm[cl][2] = m10; lm[cl][3] = m11; }
    lu[cl][j] = u0; lu[cl][6 + j] = u1;
    __syncthreads();
    // phase 2: Hillis-Steele over CPB elements; u-combine parallel across j
    for (int off = 1; off < CPB; off <<= 1) {
        bool act = (cl >= off);
        float M0, M1, M2, M3, P0, P1, P2, P3, pu0, pu1;
        if (act) {
            M0 = lm[cl][0]; M1 = lm[cl][1]; M2 = lm[cl][2]; M3 = lm[cl][3];
            P0 = lm[cl - off][0]; P1 = lm[cl - off][1];
            P2 = lm[cl - off][2]; P3 = lm[cl - off][3];
            pu0 = lu[cl - off][j]; pu1 = lu[cl - off][6 + j];
        }
        __syncthreads();
        if (act) {
            float nu0 = M0 * pu0 + M1 * pu1 + u0;
            float nu1 = M2 * pu0 + M3 * pu1 + u1;
            u0 = nu0; u1 = nu1;
            lu[cl][j] = u0; lu[cl][6 + j] = u1;
            if (j == 0) {
                lm[cl][0] = M0 * P0 + M1 * P2; lm[cl][1] = M0 * P1 + M1 * P3;
                lm[cl][2] = M2 * P0 + M3 * P2; lm[cl][3] = M2 * P1 + M3 * P3;
            }
        }
        __syncthreads();
    }
    // phase 3: coalesced write of local prefixes + block total
    for (int w = tid; w < CPB * 16; w += K2T) {
        int cc = w >> 4, k = w & 15;
        float v = (k < 4) ? lm[cc][k] : lu[cc][k - 4];
        lp[(b * CPB + cc) * 16 + k] = v;
    }
    if (tid < 16) {
        float v = (tid < 4) ? lm[CPB - 1][tid] : lu[CPB - 1][tid - 4];
        btot[b * 16 + tid] = v;
    }
}

__device__ __forceinline__ void compose(const float* L, const float* E, float* D) {
    // D = L ∘ E  (E applied first): M = ML*ME, u = ML*uE + uL
    float n00 = L[0] * E[0] + L[1] * E[2];
    float n01 = L[0] * E[1] + L[1] * E[3];
    float n10 = L[2] * E[0] + L[3] * E[2];
    float n11 = L[2] * E[1] + L[3] * E[3];
#pragma unroll
    for (int j = 0; j < 6; ++j) {
        float e0 = E[4 + j], e1 = E[10 + j];
        D[4 + j]  = L[0] * e0 + L[1] * e1 + L[4 + j];
        D[10 + j] = L[2] * e0 + L[3] * e1 + L[10 + j];
    }
    D[0] = n00; D[1] = n01; D[2] = n10; D[3] = n11;
}

// K3: one-wave scan over NBLK block totals -> inclusive block prefixes.
__global__ __launch_bounds__(64) void k_bscan(const float* __restrict__ btot,
                                             float* __restrict__ binc) {
    __shared__ float ld[NBLK * 16];
    int t = threadIdx.x;
    float S[16];
#pragma unroll
    for (int k = 0; k < 16; ++k) { S[k] = btot[t * 16 + k]; ld[t * 16 + k] = S[k]; }
    __syncthreads();
    for (int off = 1; off < NBLK; off <<= 1) {
        bool act = (t >= off);
        float P[16];
        if (act) {
#pragma unroll
            for (int k = 0; k < 16; ++k) P[k] = ld[(t - off) * 16 + k];
        }
        __syncthreads();
        if (act) {
            float D[16];
            compose(S, P, D);
#pragma unroll
            for (int k = 0; k < 16; ++k) { S[k] = D[k]; ld[t * 16 + k] = S[k]; }
        }
        __syncthreads();
    }
#pragma unroll
    for (int k = 0; k < 16; ++k) binc[t * 16 + k] = S[k];
}

// K4: per-(chunk,coord) replay. Start state derived in-thread from
// localprefix(c-1) ∘ blockprefix(b-1) applied to z1.
__global__ __launch_bounds__(256) void k_emit(
    const float* __restrict__ meas, const float* __restrict__ ws_f,
    const int* __restrict__ ws_i, const float* __restrict__ lp,
    const float* __restrict__ binc, float* __restrict__ out, int use_mt) {
    int g = blockIdx.x * 256 + threadIdx.x;
    if (g >= NCJ) return;
    int j = g >> 13;
    int c = g & (NCHUNK - 1);
    int b = c >> 7, cl = c & (CPB - 1);
    float* est  = out;
    float* pred = out + T_LEN * 6;
    float* vel  = out + T_LEN * 12;
    if (c == 0) {
        float m0 = meas[j], m1 = meas[6 + j];
        est[j] = m0; est[6 + j] = m1;
        pred[j] = m0; pred[6 + j] = m1;
        vel[j] = m1 - m0;
    }
    // z1 then apply block prefix then local prefix
    float zx = meas[6 + j], zy = meas[j];
    if (b > 0) {
        const float* B = binc + (b - 1) * 16;
        float nx = B[0] * zx + B[1] * zy + B[4 + j];
        float ny = B[2] * zx + B[3] * zy + B[10 + j];
        zx = nx; zy = ny;
    }
    if (cl > 0) {
        const float* L = lp + (c - 1) * 16;
        float nx = L[0] * zx + L[1] * zy + L[4 + j];
        float ny = L[2] * zx + L[3] * zy + L[10 + j];
        zx = nx; zy = ny;
    }
    float x = zx, y = zy;
    int sc = ws_i[0];
    float k1s = ws_f[OFF_STEADY / 4], k2s = ws_f[OFF_STEADY / 4 + 1];
    const float* k1a = ws_f + OFF_K1 / 4;
    const float* k2a = ws_f + OFF_K2 / 4;
    const float* mT  = ws_f + OFF_MT / 4;
    int s0 = c * CHUNK;
#pragma unroll
    for (int i = 0; i < CHUNK; ++i) {
        int s = s0 + i;
        if (s < NSTEPS) {
            float g1, g2;
            load_gains(s, sc, k1a, k2a, k1s, k2s, g1, g2);
            float mj = use_mt ? mT[(i * 6 + j) * NCHUNK + c]
                              : meas[(s + 2) * 6 + j];
            float vx  = x - y;
            float p   = x + vx;
            float inn = mj - p;
            float xn  = p + g1 * inn;
            float yn  = x + g2 * inn;
            est[(s + 2) * 6 + j]  = xn;
            pred[(s + 2) * 6 + j] = p;
            if (s < NSTEPS - 1) vel[(s + 1) * 6 + j] = xn - yn;
            x = xn; y = yn;
        }
    }
}

extern "C" void kernel_launch(void* const* d_in, const int* in_sizes, int n_in,
                              void* d_out, int out_size, void* d_ws, size_t ws_size,
                              hipStream_t stream) {
    const float* meas = (const float*)d_in[0];
    const float* pnc  = (const float*)d_in[1];
    const float* mnc  = (const float*)d_in[2];
    const float* cov  = (const float*)d_in[3];
    float* ws_f = (float*)d_ws;
    int*   ws_i = (int*)d_ws;
    float* lp   = ws_f + OFF_LP / 4;
    float* btot = ws_f + OFF_BT / 4;
    float* binc = ws_f + OFF_BI / 4;
    float* out  = (float*)d_out;

    int use_mt = (ws_size >= WS_NEED) ? 1 : 0;
    int xb = use_mt ? 1 + MT_FLOATS / 256 : 1;
    k_gains_xpose<<<xb, 256, 0, stream>>>(pnc, mnc, cov, meas, ws_f, ws_i, use_mt);
    k_chunk_scan<<<NBLK, K2T, 0, stream>>>(meas, ws_f, ws_i, lp, btot, use_mt);
    k_bscan<<<1, NBLK, 0, stream>>>(btot, binc);
    k_emit<<<NCJ / 256, 256, 0, stream>>>(meas, ws_f, ws_i, lp, binc, out, use_mt);
}

// Round 12
// 86.919 us; speedup vs baseline: 7.4857x; 1.0726x over previous
//
#include <hip/hip_runtime.h>

#define T_LEN   131072
#define NSTEPS  (T_LEN - 2)      // 131070 scan steps (measurements 2..T-1)
#define CHUNK   16
#define NCHUNK  8192             // 8192*16 = 131072 >= NSTEPS
#define NCJ     (NCHUNK * 6)     // 49152 (chunk,coord) lanes
#define CAP     512
#define CPB     128              // chunks per scan block
#define NBLK    (NCHUNK / CPB)   // 64
#define K2T     (CPB * 6)        // 768 threads

// workspace byte offsets (16B aligned)
#define OFF_STEADY 16
#define OFF_K1     32
#define OFF_K2     (OFF_K1 + CAP * 4)            // 2080
#define OFF_LP     (OFF_K2 + CAP * 4)            // 4128; NCHUNK*16 floats (512KB)
#define OFF_BT     (OFF_LP + NCHUNK * 16 * 4)    // NBLK*16 floats
#define OFF_BI     (OFF_BT + NBLK * 16 * 4)
#define OFF_MT     (OFF_BI + NBLK * 16 * 4)
#define MT_FLOATS  (CHUNK * 6 * NCHUNK)          // 786432 (3MB)
#define WS_NEED    ((size_t)OFF_MT + (size_t)MT_FLOATS * 4)   // ~3.6MB

// K1 (block 0): serial scalar Riccati. Blocks >0: transpose meas -> mT[i][j][c].
__global__ __launch_bounds__(256) void k_gains_xpose(
    const float* __restrict__ pnc, const float* __restrict__ mnc,
    const float* __restrict__ cov, const float* __restrict__ meas,
    float* __restrict__ ws_f, int* __restrict__ ws_i, int do_xpose) {
    if (blockIdx.x == 0) {
        if (threadIdx.x != 0) return;
        float q = pnc[0];
        float r = mnc[0];
        float a = cov[0];
        float b = cov[6];
        float c = cov[6 * 12 + 6];
        float* k1a = ws_f + OFF_K1 / 4;
        float* k2a = ws_f + OFF_K2 / 4;
        float pk1 = -1e30f, pk2 = -1e30f;
        float k1 = 0.f, k2 = 0.f;
        int stable = 0;
        int s;
        for (s = 0; s < CAP; ++s) {
            float bp = 2.0f * a - b;
            float t2 = 2.0f * b - c;
            float ap = 2.0f * bp - t2 + q;
            float cp = a;
            float S  = ap + r;
            float invS = 1.0f / S;
            k1 = ap * invS;
            k2 = bp * invS;
            k1a[s] = k1;
            k2a[s] = k2;
            float om = 1.0f - k1;
            a = om * ap;
            b = om * bp;
            c = cp - k2 * bp;
            if (fabsf(k1 - pk1) <= 5e-7f * fabsf(k1) &&
                fabsf(k2 - pk2) <= 5e-7f * (fabsf(k2) + 1e-20f)) {
                if (++stable >= 8) { ++s; break; }
            } else {
                stable = 0;
            }
            pk1 = k1; pk2 = k2;
        }
        ws_i[0] = s;
        ws_f[OFF_STEADY / 4]     = k1;
        ws_f[OFF_STEADY / 4 + 1] = k2;
        return;
    }
    if (!do_xpose) return;
    int w = (blockIdx.x - 1) * 256 + threadIdx.x;   // 0 .. MT_FLOATS-1
    if (w >= MT_FLOATS) return;
    int c = w & (NCHUNK - 1);
    int f = w >> 13;             // i*6 + j, 0..95
    int i = f / 6, j = f - 6 * i;
    int s = c * CHUNK + i;
    float v = (s < NSTEPS) ? meas[(s + 2) * 6 + j] : 0.f;
    ws_f[OFF_MT / 4 + w] = v;
}

__device__ __forceinline__ void load_gains(int s, int sc, const float* k1a,
                                           const float* k2a, float k1s, float k2s,
                                           float& g1, float& g2) {
    int si = (s < sc) ? s : 0;
    float a = k1a[si], b = k2a[si];
    g1 = (s < sc) ? a : k1s;
    g2 = (s < sc) ? b : k2s;
}

// K2: per-(chunk,coord) composition + intra-block Hillis-Steele local scan.
// Writes per-chunk local prefixes (lp) and per-block totals (btot).
__global__ __launch_bounds__(K2T) void k_chunk_scan(
    const float* __restrict__ meas, const float* __restrict__ ws_f,
    const int* __restrict__ ws_i, float* __restrict__ lp,
    float* __restrict__ btot, int use_mt) {
    __shared__ float lm[CPB][5];    // 2x2 M per chunk (pad 5 vs bank conflicts)
    __shared__ float lu[CPB][13];   // u0[6],u1[6] per chunk (pad 13)
    int tid = threadIdx.x;
    int cl = tid & (CPB - 1);
    int j  = tid >> 7;              // 0..5
    int b  = blockIdx.x;
    int c  = b * CPB + cl;
    int sc = ws_i[0];
    float k1s = ws_f[OFF_STEADY / 4], k2s = ws_f[OFF_STEADY / 4 + 1];
    const float* k1a = ws_f + OFF_K1 / 4;
    const float* k2a = ws_f + OFF_K2 / 4;
    const float* mT  = ws_f + OFF_MT / 4;
    // phase 1: chunk composition (M redundant per j; u per (chunk, coord))
    int s0 = c * CHUNK;
    float m00 = 1.f, m01 = 0.f, m10 = 0.f, m11 = 1.f;
    float u0 = 0.f, u1 = 0.f;
#pragma unroll
    for (int i = 0; i < CHUNK; ++i) {
        int s = s0 + i;
        if (s < NSTEPS) {
            float g1, g2;
            load_gains(s, sc, k1a, k2a, k1s, k2s, g1, g2);
            float om  = 1.0f - g1;
            float a00 = 2.0f * om, a01 = -om;
            float a10 = 1.0f - 2.0f * g2, a11 = g2;
            float n00 = a00 * m00 + a01 * m10;
            float n01 = a00 * m01 + a01 * m11;
            float n10 = a10 * m00 + a11 * m10;
            float n11 = a10 * m01 + a11 * m11;
            m00 = n00; m01 = n01; m10 = n10; m11 = n11;
            float mj = use_mt ? mT[(i * 6 + j) * NCHUNK + c]
                              : meas[(s + 2) * 6 + j];
            float v0 = a00 * u0 + a01 * u1 + g1 * mj;
            float v1 = a10 * u0 + a11 * u1 + g2 * mj;
            u0 = v0; u1 = v1;
        }
    }
    if (j == 0) { lm[cl][0] = m00; lm[cl][1] = m01; lm[cl][2] = m10; lm[cl][3] = m11; }
    lu[cl][j] = u0; lu[cl][6 + j] = u1;
    __syncthreads();
    // phase 2: Hillis-Steele over CPB elements; u-combine parallel across j
    for (int off = 1; off < CPB; off <<= 1) {
        bool act = (cl >= off);
        float M0, M1, M2, M3, P0, P1, P2, P3, pu0, pu1;
        if (act) {
            M0 = lm[cl][0]; M1 = lm[cl][1]; M2 = lm[cl][2]; M3 = lm[cl][3];
            P0 = lm[cl - off][0]; P1 = lm[cl - off][1];
            P2 = lm[cl - off][2]; P3 = lm[cl - off][3];
            pu0 = lu[cl - off][j]; pu1 = lu[cl - off][6 + j];
        }
        __syncthreads();
        if (act) {
            float nu0 = M0 * pu0 + M1 * pu1 + u0;
            float nu1 = M2 * pu0 + M3 * pu1 + u1;
            u0 = nu0; u1 = nu1;
            lu[cl][j] = u0; lu[cl][6 + j] = u1;
            if (j == 0) {
                lm[cl][0] = M0 * P0 + M1 * P2; lm[cl][1] = M0 * P1 + M1 * P3;
                lm[cl][2] = M2 * P0 + M3 * P2; lm[cl][3] = M2 * P1 + M3 * P3;
            }
        }
        __syncthreads();
    }
    // phase 3: coalesced write of local prefixes + block total
    for (int w = tid; w < CPB * 16; w += K2T) {
        int cc = w >> 4, k = w & 15;
        float v = (k < 4) ? lm[cc][k] : lu[cc][k - 4];
        lp[(b * CPB + cc) * 16 + k] = v;
    }
    if (tid < 16) {
        float v = (tid < 4) ? lm[CPB - 1][tid] : lu[CPB - 1][tid - 4];
        btot[b * 16 + tid] = v;
    }
}

__device__ __forceinline__ void compose(const float* L, const float* E, float* D) {
    // D = L ∘ E  (E applied first): M = ML*ME, u = ML*uE + uL
    float n00 = L[0] * E[0] + L[1] * E[2];
    float n01 = L[0] * E[1] + L[1] * E[3];
    float n10 = L[2] * E[0] + L[3] * E[2];
    float n11 = L[2] * E[1] + L[3] * E[3];
#pragma unroll
    for (int j = 0; j < 6; ++j) {
        float e0 = E[4 + j], e1 = E[10 + j];
        D[4 + j]  = L[0] * e0 + L[1] * e1 + L[4 + j];
        D[10 + j] = L[2] * e0 + L[3] * e1 + L[10 + j];
    }
    D[0] = n00; D[1] = n01; D[2] = n10; D[3] = n11;
}

// K3: one-wave scan over NBLK block totals -> inclusive block prefixes.
__global__ __launch_bounds__(64) void k_bscan(const float* __restrict__ btot,
                                             float* __restrict__ binc) {
    __shared__ float ld[NBLK * 16];
    int t = threadIdx.x;
    float S[16];
#pragma unroll
    for (int k = 0; k < 16; ++k) { S[k] = btot[t * 16 + k]; ld[t * 16 + k] = S[k]; }
    __syncthreads();
    for (int off = 1; off < NBLK; off <<= 1) {
        bool act = (t >= off);
        float P[16];
        if (act) {
#pragma unroll
            for (int k = 0; k < 16; ++k) P[k] = ld[(t - off) * 16 + k];
        }
        __syncthreads();
        if (act) {
            float D[16];
            compose(S, P, D);
#pragma unroll
            for (int k = 0; k < 16; ++k) { S[k] = D[k]; ld[t * 16 + k] = S[k]; }
        }
        __syncthreads();
    }
#pragma unroll
    for (int k = 0; k < 16; ++k) binc[t * 16 + k] = S[k];
}

// K4: per-(chunk,coord) replay. j-fastest lane mapping (c = g/6, j = g%6):
// wave stores hit ~11 contiguous 24B runs instead of 64 scattered dwords,
// and direct meas reads coalesce the same way (mT no longer needed here).
__global__ __launch_bounds__(256) void k_emit(
    const float* __restrict__ meas, const float* __restrict__ ws_f,
    const int* __restrict__ ws_i, const float* __restrict__ lp,
    const float* __restrict__ binc, float* __restrict__ out) {
    int g = blockIdx.x * 256 + threadIdx.x;
    if (g >= NCJ) return;
    int c = g / 6;
    int j = g - 6 * c;
    int b = c >> 7, cl = c & (CPB - 1);
    float* est  = out;
    float* pred = out + T_LEN * 6;
    float* vel  = out + T_LEN * 12;
    if (c == 0) {
        float m0 = meas[j], m1 = meas[6 + j];
        est[j] = m0; est[6 + j] = m1;
        pred[j] = m0; pred[6 + j] = m1;
        vel[j] = m1 - m0;
    }
    // z1 then apply block prefix then local prefix
    float zx = meas[6 + j], zy = meas[j];
    if (b > 0) {
        const float* B = binc + (b - 1) * 16;
        float nx = B[0] * zx + B[1] * zy + B[4 + j];
        float ny = B[2] * zx + B[3] * zy + B[10 + j];
        zx = nx; zy = ny;
    }
    if (cl > 0) {
        const float* L = lp + (c - 1) * 16;
        float nx = L[0] * zx + L[1] * zy + L[4 + j];
        float ny = L[2] * zx + L[3] * zy + L[10 + j];
        zx = nx; zy = ny;
    }
    float x = zx, y = zy;
    int sc = ws_i[0];
    float k1s = ws_f[OFF_STEADY / 4], k2s = ws_f[OFF_STEADY / 4 + 1];
    const float* k1a = ws_f + OFF_K1 / 4;
    const float* k2a = ws_f + OFF_K2 / 4;
    int s0 = c * CHUNK;
#pragma unroll
    for (int i = 0; i < CHUNK; ++i) {
        int s = s0 + i;
        if (s < NSTEPS) {
            float g1, g2;
            load_gains(s, sc, k1a, k2a, k1s, k2s, g1, g2);
            float mj  = meas[(s + 2) * 6 + j];
            float vx  = x - y;
            float p   = x + vx;
            float inn = mj - p;
            float xn  = p + g1 * inn;
            float yn  = x + g2 * inn;
            est[(s + 2) * 6 + j]  = xn;
            pred[(s + 2) * 6 + j] = p;
            if (s < NSTEPS - 1) vel[(s + 1) * 6 + j] = xn - yn;
            x = xn; y = yn;
        }
    }
}

extern "C" void kernel_launch(void* const* d_in, const int* in_sizes, int n_in,
                              void* d_out, int out_size, void* d_ws, size_t ws_size,
                              hipStream_t stream) {
    const float* meas = (const float*)d_in[0];
    const float* pnc  = (const float*)d_in[1];
    const float* mnc  = (const float*)d_in[2];
    const float* cov  = (const float*)d_in[3];
    float* ws_f = (float*)d_ws;
    int*   ws_i = (int*)d_ws;
    float* lp   = ws_f + OFF_LP / 4;
    float* btot = ws_f + OFF_BT / 4;
    float* binc = ws_f + OFF_BI / 4;
    float* out  = (float*)d_out;

    int use_mt = (ws_size >= WS_NEED) ? 1 : 0;
    int xb = use_mt ? 1 + MT_FLOATS / 256 : 1;
    k_gains_xpose<<<xb, 256, 0, stream>>>(pnc, mnc, cov, meas, ws_f, ws_i, use_mt);
    k_chunk_scan<<<NBLK, K2T, 0, stream>>>(meas, ws_f, ws_i, lp, btot, use_mt);
    k_bscan<<<1, NBLK, 0, stream>>>(btot, binc);
    k_emit<<<NCJ / 256, 256, 0, stream>>>(meas, ws_f, ws_i, lp, binc, out);
}

// Round 13
// 84.225 us; speedup vs baseline: 7.7251x; 1.0320x over previous
//
#include <hip/hip_runtime.h>

#define T_LEN   131072
#define NSTEPS  (T_LEN - 2)      // 131070 scan steps (measurements 2..T-1)
#define CHUNK   16
#define NCHUNK  8192             // 8192*16 = 131072 >= NSTEPS
#define NCJ     (NCHUNK * 6)     // 49152 (chunk,coord) lanes
#define CAP     512
#define CPB     128              // chunks per scan block
#define NBLK    (NCHUNK / CPB)   // 64
#define K2T     (CPB * 6)        // 768 threads

// workspace byte offsets (16B aligned)
#define OFF_STEADY 16
#define OFF_K1     32
#define OFF_K2     (OFF_K1 + CAP * 4)            // 2080
#define OFF_LP     (OFF_K2 + CAP * 4)            // 4128; NCHUNK*16 floats (512KB)
#define OFF_BT     (OFF_LP + NCHUNK * 16 * 4)    // NBLK*16 floats
#define OFF_BI     (OFF_BT + NBLK * 16 * 4)

// K1: serial scalar Riccati (single block, single thread).
__global__ __launch_bounds__(64) void k_gains(
    const float* __restrict__ pnc, const float* __restrict__ mnc,
    const float* __restrict__ cov, float* __restrict__ ws_f,
    int* __restrict__ ws_i) {
    if (threadIdx.x != 0 || blockIdx.x != 0) return;
    float q = pnc[0];
    float r = mnc[0];
    float a = cov[0];
    float b = cov[6];
    float c = cov[6 * 12 + 6];
    float* k1a = ws_f + OFF_K1 / 4;
    float* k2a = ws_f + OFF_K2 / 4;
    float pk1 = -1e30f, pk2 = -1e30f;
    float k1 = 0.f, k2 = 0.f;
    int stable = 0;
    int s;
    for (s = 0; s < CAP; ++s) {
        float bp = 2.0f * a - b;
        float t2 = 2.0f * b - c;
        float ap = 2.0f * bp - t2 + q;
        float cp = a;
        float S  = ap + r;
        float invS = 1.0f / S;
        k1 = ap * invS;
        k2 = bp * invS;
        k1a[s] = k1;
        k2a[s] = k2;
        float om = 1.0f - k1;
        a = om * ap;
        b = om * bp;
        c = cp - k2 * bp;
        if (fabsf(k1 - pk1) <= 5e-7f * fabsf(k1) &&
            fabsf(k2 - pk2) <= 5e-7f * (fabsf(k2) + 1e-20f)) {
            if (++stable >= 8) { ++s; break; }
        } else {
            stable = 0;
        }
        pk1 = k1; pk2 = k2;
    }
    ws_i[0] = s;
    ws_f[OFF_STEADY / 4]     = k1;
    ws_f[OFF_STEADY / 4 + 1] = k2;
}

__device__ __forceinline__ void load_gains(int s, int sc, const float* k1a,
                                           const float* k2a, float k1s, float k2s,
                                           float& g1, float& g2) {
    int si = (s < sc) ? s : 0;
    float a = k1a[si], b = k2a[si];
    g1 = (s < sc) ? a : k1s;
    g2 = (s < sc) ? b : k2s;
}

// K2: per-(chunk,coord) composition + intra-block Hillis-Steele local scan.
// j-fastest lane mapping: direct meas reads coalesce (~11 rows/wave).
__global__ __launch_bounds__(K2T) void k_chunk_scan(
    const float* __restrict__ meas, const float* __restrict__ ws_f,
    const int* __restrict__ ws_i, float* __restrict__ lp,
    float* __restrict__ btot) {
    __shared__ float lm[CPB][5];    // 2x2 M per chunk (pad 5 vs bank conflicts)
    __shared__ float lu[CPB][13];   // u0[6],u1[6] per chunk (pad 13)
    int tid = threadIdx.x;
    int cl = tid / 6;               // chunk-in-block 0..127
    int j  = tid - 6 * cl;          // coord 0..5
    int b  = blockIdx.x;
    int c  = b * CPB + cl;
    int sc = ws_i[0];
    float k1s = ws_f[OFF_STEADY / 4], k2s = ws_f[OFF_STEADY / 4 + 1];
    const float* k1a = ws_f + OFF_K1 / 4;
    const float* k2a = ws_f + OFF_K2 / 4;
    // phase 1: chunk composition (M redundant per j; u per (chunk, coord))
    int s0 = c * CHUNK;
    float m00 = 1.f, m01 = 0.f, m10 = 0.f, m11 = 1.f;
    float u0 = 0.f, u1 = 0.f;
#pragma unroll
    for (int i = 0; i < CHUNK; ++i) {
        int s = s0 + i;
        if (s < NSTEPS) {
            float g1, g2;
            load_gains(s, sc, k1a, k2a, k1s, k2s, g1, g2);
            float om  = 1.0f - g1;
            float a00 = 2.0f * om, a01 = -om;
            float a10 = 1.0f - 2.0f * g2, a11 = g2;
            float n00 = a00 * m00 + a01 * m10;
            float n01 = a00 * m01 + a01 * m11;
            float n10 = a10 * m00 + a11 * m10;
            float n11 = a10 * m01 + a11 * m11;
            m00 = n00; m01 = n01; m10 = n10; m11 = n11;
            float mj = meas[(s + 2) * 6 + j];
            float v0 = a00 * u0 + a01 * u1 + g1 * mj;
            float v1 = a10 * u0 + a11 * u1 + g2 * mj;
            u0 = v0; u1 = v1;
        }
    }
    if (j == 0) { lm[cl][0] = m00; lm[cl][1] = m01; lm[cl][2] = m10; lm[cl][3] = m11; }
    lu[cl][j] = u0; lu[cl][6 + j] = u1;
    __syncthreads();
    // phase 2: Hillis-Steele over CPB elements; u-combine parallel across j
    for (int off = 1; off < CPB; off <<= 1) {
        bool act = (cl >= off);
        float M0, M1, M2, M3, P0, P1, P2, P3, pu0, pu1;
        if (act) {
            M0 = lm[cl][0]; M1 = lm[cl][1]; M2 = lm[cl][2]; M3 = lm[cl][3];
            P0 = lm[cl - off][0]; P1 = lm[cl - off][1];
            P2 = lm[cl - off][2]; P3 = lm[cl - off][3];
            pu0 = lu[cl - off][j]; pu1 = lu[cl - off][6 + j];
        }
        __syncthreads();
        if (act) {
            float nu0 = M0 * pu0 + M1 * pu1 + u0;
            float nu1 = M2 * pu0 + M3 * pu1 + u1;
            u0 = nu0; u1 = nu1;
            lu[cl][j] = u0; lu[cl][6 + j] = u1;
            if (j == 0) {
                lm[cl][0] = M0 * P0 + M1 * P2; lm[cl][1] = M0 * P1 + M1 * P3;
                lm[cl][2] = M2 * P0 + M3 * P2; lm[cl][3] = M2 * P1 + M3 * P3;
            }
        }
        __syncthreads();
    }
    // phase 3: coalesced write of local prefixes + block total
    for (int w = tid; w < CPB * 16; w += K2T) {
        int cc = w >> 4, k = w & 15;
        float v = (k < 4) ? lm[cc][k] : lu[cc][k - 4];
        lp[(b * CPB + cc) * 16 + k] = v;
    }
    if (tid < 16) {
        float v = (tid < 4) ? lm[CPB - 1][tid] : lu[CPB - 1][tid - 4];
        btot[b * 16 + tid] = v;
    }
}

__device__ __forceinline__ void compose(const float* L, const float* E, float* D) {
    // D = L ∘ E  (E applied first): M = ML*ME, u = ML*uE + uL
    float n00 = L[0] * E[0] + L[1] * E[2];
    float n01 = L[0] * E[1] + L[1] * E[3];
    float n10 = L[2] * E[0] + L[3] * E[2];
    float n11 = L[2] * E[1] + L[3] * E[3];
#pragma unroll
    for (int j = 0; j < 6; ++j) {
        float e0 = E[4 + j], e1 = E[10 + j];
        D[4 + j]  = L[0] * e0 + L[1] * e1 + L[4 + j];
        D[10 + j] = L[2] * e0 + L[3] * e1 + L[10 + j];
    }
    D[0] = n00; D[1] = n01; D[2] = n10; D[3] = n11;
}

// K3: one-wave scan over NBLK block totals -> inclusive block prefixes.
__global__ __launch_bounds__(64) void k_bscan(const float* __restrict__ btot,
                                             float* __restrict__ binc) {
    __shared__ float ld[NBLK * 16];
    int t = threadIdx.x;
    float S[16];
#pragma unroll
    for (int k = 0; k < 16; ++k) { S[k] = btot[t * 16 + k]; ld[t * 16 + k] = S[k]; }
    __syncthreads();
    for (int off = 1; off < NBLK; off <<= 1) {
        bool act = (t >= off);
        float P[16];
        if (act) {
#pragma unroll
            for (int k = 0; k < 16; ++k) P[k] = ld[(t - off) * 16 + k];
        }
        __syncthreads();
        if (act) {
            float D[16];
            compose(S, P, D);
#pragma unroll
            for (int k = 0; k < 16; ++k) { S[k] = D[k]; ld[t * 16 + k] = S[k]; }
        }
        __syncthreads();
    }
#pragma unroll
    for (int k = 0; k < 16; ++k) binc[t * 16 + k] = S[k];
}

// K4: per-(chunk,coord) replay, j-fastest mapping (proven round 12).
__global__ __launch_bounds__(256) void k_emit(
    const float* __restrict__ meas, const float* __restrict__ ws_f,
    const int* __restrict__ ws_i, const float* __restrict__ lp,
    const float* __restrict__ binc, float* __restrict__ out) {
    int g = blockIdx.x * 256 + threadIdx.x;
    if (g >= NCJ) return;
    int c = g / 6;
    int j = g - 6 * c;
    int b = c >> 7, cl = c & (CPB - 1);
    float* est  = out;
    float* pred = out + T_LEN * 6;
    float* vel  = out + T_LEN * 12;
    if (c == 0) {
        float m0 = meas[j], m1 = meas[6 + j];
        est[j] = m0; est[6 + j] = m1;
        pred[j] = m0; pred[6 + j] = m1;
        vel[j] = m1 - m0;
    }
    // z1 then apply block prefix then local prefix
    float zx = meas[6 + j], zy = meas[j];
    if (b > 0) {
        const float* B = binc + (b - 1) * 16;
        float nx = B[0] * zx + B[1] * zy + B[4 + j];
        float ny = B[2] * zx + B[3] * zy + B[10 + j];
        zx = nx; zy = ny;
    }
    if (cl > 0) {
        const float* L = lp + (c - 1) * 16;
        float nx = L[0] * zx + L[1] * zy + L[4 + j];
        float ny = L[2] * zx + L[3] * zy + L[10 + j];
        zx = nx; zy = ny;
    }
    float x = zx, y = zy;
    int sc = ws_i[0];
    float k1s = ws_f[OFF_STEADY / 4], k2s = ws_f[OFF_STEADY / 4 + 1];
    const float* k1a = ws_f + OFF_K1 / 4;
    const float* k2a = ws_f + OFF_K2 / 4;
    int s0 = c * CHUNK;
#pragma unroll
    for (int i = 0; i < CHUNK; ++i) {
        int s = s0 + i;
        if (s < NSTEPS) {
            float g1, g2;
            load_gains(s, sc, k1a, k2a, k1s, k2s, g1, g2);
            float mj  = meas[(s + 2) * 6 + j];
            float vx  = x - y;
            float p   = x + vx;
            float inn = mj - p;
            float xn  = p + g1 * inn;
            float yn  = x + g2 * inn;
            est[(s + 2) * 6 + j]  = xn;
            pred[(s + 2) * 6 + j] = p;
            if (s < NSTEPS - 1) vel[(s + 1) * 6 + j] = xn - yn;
            x = xn; y = yn;
        }
    }
}

extern "C" void kernel_launch(void* const* d_in, const int* in_sizes, int n_in,
                              void* d_out, int out_size, void* d_ws, size_t ws_size,
                              hipStream_t stream) {
    const float* meas = (const float*)d_in[0];
    const float* pnc  = (const float*)d_in[1];
    const float* mnc  = (const float*)d_in[2];
    const float* cov  = (const float*)d_in[3];
    float* ws_f = (float*)d_ws;
    int*   ws_i = (int*)d_ws;
    float* lp   = ws_f + OFF_LP / 4;
    float* btot = ws_f + OFF_BT / 4;
    float* binc = ws_f + OFF_BI / 4;
    float* out  = (float*)d_out;

    k_gains<<<1, 64, 0, stream>>>(pnc, mnc, cov, ws_f, ws_i);
    k_chunk_scan<<<NBLK, K2T, 0, stream>>>(meas, ws_f, ws_i, lp, btot);
    k_bscan<<<1, NBLK, 0, stream>>>(btot, binc);
    k_emit<<<NCJ / 256, 256, 0, stream>>>(meas, ws_f, ws_i, lp, binc, out);
}

// Round 14
// 82.320 us; speedup vs baseline: 7.9039x; 1.0231x over previous
//
#include <hip/hip_runtime.h>

#define T_LEN   131072
#define NSTEPS  (T_LEN - 2)      // 131070 scan steps (measurements 2..T-1)
#define CHUNK   16
#define NCHUNK  8192             // 8192*16 = 131072 >= NSTEPS
#define NCJ     (NCHUNK * 6)     // 49152 (chunk,coord) lanes
#define CAP     512
#define CPB     64               // chunks per scan block
#define NBLK    (NCHUNK / CPB)   // 128 blocks
#define K2T     (CPB * 6)        // 384 threads

// workspace byte offsets (16B aligned)
#define OFF_STEADY 16
#define OFF_K1     32
#define OFF_K2     (OFF_K1 + CAP * 4)            // 2080
#define OFF_LP     (OFF_K2 + CAP * 4)            // 4128; NCHUNK*16 floats (512KB)
#define OFF_BT     (OFF_LP + NCHUNK * 16 * 4)    // NBLK*16 floats
#define OFF_BI     (OFF_BT + NBLK * 16 * 4)

// Riccati recursion (scalar block form); returns #stored gains, fills LDS table.
__device__ __forceinline__ int riccati(const float* pnc, const float* mnc,
                                       const float* cov, float* g1t, float* g2t,
                                       float& k1o, float& k2o) {
    float q = pnc[0], r = mnc[0];
    float a = cov[0], b = cov[6], c = cov[6 * 12 + 6];
    float pk1 = -1e30f, pk2 = -1e30f, k1 = 0.f, k2 = 0.f;
    int stable = 0, s;
    for (s = 0; s < CAP; ++s) {
        float bp = 2.0f * a - b;
        float t2 = 2.0f * b - c;
        float ap = 2.0f * bp - t2 + q;
        float cp = a;
        float S  = ap + r;
        float invS = 1.0f / S;
        k1 = ap * invS;
        k2 = bp * invS;
        g1t[s] = k1;
        g2t[s] = k2;
        float om = 1.0f - k1;
        a = om * ap;
        b = om * bp;
        c = cp - k2 * bp;
        if (fabsf(k1 - pk1) <= 5e-7f * fabsf(k1) &&
            fabsf(k2 - pk2) <= 5e-7f * (fabsf(k2) + 1e-20f)) {
            if (++stable >= 8) { ++s; break; }
        } else {
            stable = 0;
        }
        pk1 = k1; pk2 = k2;
    }
    k1o = k1; k2o = k2;
    return s;
}

// K1: per-block redundant Riccati (thread 0 -> LDS) + chunk composition +
// intra-block Hillis-Steele scan. Block 0 also publishes gains to ws for k_emit.
__global__ __launch_bounds__(K2T) void k_chunk_scan(
    const float* __restrict__ meas, const float* __restrict__ pnc,
    const float* __restrict__ mnc, const float* __restrict__ cov,
    float* __restrict__ ws_f, int* __restrict__ ws_i,
    float* __restrict__ lp, float* __restrict__ btot) {
    __shared__ float g1t[CAP], g2t[CAP];     // 4KB gain table
    __shared__ float lm[CPB][5];             // 2x2 M per chunk (pad 5)
    __shared__ float lu[CPB][13];            // u0[6],u1[6] per chunk (pad 13)
    __shared__ int   s_sc;
    __shared__ float s_k1, s_k2;
    int tid = threadIdx.x;
    int cl = tid / 6;               // chunk-in-block 0..63
    int j  = tid - 6 * cl;          // coord 0..5
    int b  = blockIdx.x;
    if (tid == 0) {
        float k1, k2;
        int sc = riccati(pnc, mnc, cov, g1t, g2t, k1, k2);
        s_sc = sc; s_k1 = k1; s_k2 = k2;
    }
    __syncthreads();
    int sc = s_sc;
    float k1s = s_k1, k2s = s_k2;
    // block 0 publishes gains for k_emit (kernel barrier orders this)
    if (b == 0) {
        for (int t = tid; t < sc; t += K2T) {
            ws_f[OFF_K1 / 4 + t] = g1t[t];
            ws_f[OFF_K2 / 4 + t] = g2t[t];
        }
        if (tid == 0) {
            ws_i[0] = sc;
            ws_f[OFF_STEADY / 4]     = k1s;
            ws_f[OFF_STEADY / 4 + 1] = k2s;
        }
    }
    // phase 1: chunk composition. Blocks b>0 have s >= CPB*16 >= 1024 > sc
    // always -> pure steady gains; block 0 uses the LDS table.
    int c = b * CPB + cl;
    int s0 = c * CHUNK;
    float m00 = 1.f, m01 = 0.f, m10 = 0.f, m11 = 1.f;
    float u0 = 0.f, u1 = 0.f;
#pragma unroll
    for (int i = 0; i < CHUNK; ++i) {
        int s = s0 + i;
        if (s < NSTEPS) {
            float g1, g2;
            if (b == 0) {
                int si = (s < sc) ? s : 0;
                float ta = g1t[si], tb = g2t[si];
                g1 = (s < sc) ? ta : k1s;
                g2 = (s < sc) ? tb : k2s;
            } else {
                g1 = k1s; g2 = k2s;
            }
            float om  = 1.0f - g1;
            float a00 = 2.0f * om, a01 = -om;
            float a10 = 1.0f - 2.0f * g2, a11 = g2;
            float n00 = a00 * m00 + a01 * m10;
            float n01 = a00 * m01 + a01 * m11;
            float n10 = a10 * m00 + a11 * m10;
            float n11 = a10 * m01 + a11 * m11;
            m00 = n00; m01 = n01; m10 = n10; m11 = n11;
            float mj = meas[(s + 2) * 6 + j];
            float v0 = a00 * u0 + a01 * u1 + g1 * mj;
            float v1 = a10 * u0 + a11 * u1 + g2 * mj;
            u0 = v0; u1 = v1;
        }
    }
    if (j == 0) { lm[cl][0] = m00; lm[cl][1] = m01; lm[cl][2] = m10; lm[cl][3] = m11; }
    lu[cl][j] = u0; lu[cl][6 + j] = u1;
    __syncthreads();
    // phase 2: Hillis-Steele over CPB elements; u-combine parallel across j
    for (int off = 1; off < CPB; off <<= 1) {
        bool act = (cl >= off);
        float M0, M1, M2, M3, P0, P1, P2, P3, pu0, pu1;
        if (act) {
            M0 = lm[cl][0]; M1 = lm[cl][1]; M2 = lm[cl][2]; M3 = lm[cl][3];
            P0 = lm[cl - off][0]; P1 = lm[cl - off][1];
            P2 = lm[cl - off][2]; P3 = lm[cl - off][3];
            pu0 = lu[cl - off][j]; pu1 = lu[cl - off][6 + j];
        }
        __syncthreads();
        if (act) {
            float nu0 = M0 * pu0 + M1 * pu1 + u0;
            float nu1 = M2 * pu0 + M3 * pu1 + u1;
            u0 = nu0; u1 = nu1;
            lu[cl][j] = u0; lu[cl][6 + j] = u1;
            if (j == 0) {
                lm[cl][0] = M0 * P0 + M1 * P2; lm[cl][1] = M0 * P1 + M1 * P3;
                lm[cl][2] = M2 * P0 + M3 * P2; lm[cl][3] = M2 * P1 + M3 * P3;
            }
        }
        __syncthreads();
    }
    // phase 3: coalesced write of local prefixes + block total
    for (int w = tid; w < CPB * 16; w += K2T) {
        int cc = w >> 4, k = w & 15;
        float v = (k < 4) ? lm[cc][k] : lu[cc][k - 4];
        lp[(b * CPB + cc) * 16 + k] = v;
    }
    if (tid < 16) {
        float v = (tid < 4) ? lm[CPB - 1][tid] : lu[CPB - 1][tid - 4];
        btot[b * 16 + tid] = v;
    }
}

__device__ __forceinline__ void compose(const float* L, const float* E, float* D) {
    // D = L ∘ E  (E applied first): M = ML*ME, u = ML*uE + uL
    float n00 = L[0] * E[0] + L[1] * E[2];
    float n01 = L[0] * E[1] + L[1] * E[3];
    float n10 = L[2] * E[0] + L[3] * E[2];
    float n11 = L[2] * E[1] + L[3] * E[3];
#pragma unroll
    for (int j = 0; j < 6; ++j) {
        float e0 = E[4 + j], e1 = E[10 + j];
        D[4 + j]  = L[0] * e0 + L[1] * e1 + L[4 + j];
        D[10 + j] = L[2] * e0 + L[3] * e1 + L[10 + j];
    }
    D[0] = n00; D[1] = n01; D[2] = n10; D[3] = n11;
}

// K2: scan over NBLK block totals -> inclusive block prefixes (2 waves).
__global__ __launch_bounds__(NBLK) void k_bscan(const float* __restrict__ btot,
                                                float* __restrict__ binc) {
    __shared__ float ld[NBLK * 16];
    int t = threadIdx.x;
    float S[16];
#pragma unroll
    for (int k = 0; k < 16; ++k) { S[k] = btot[t * 16 + k]; ld[t * 16 + k] = S[k]; }
    __syncthreads();
    for (int off = 1; off < NBLK; off <<= 1) {
        bool act = (t >= off);
        float P[16];
        if (act) {
#pragma unroll
            for (int k = 0; k < 16; ++k) P[k] = ld[(t - off) * 16 + k];
        }
        __syncthreads();
        if (act) {
            float D[16];
            compose(S, P, D);
#pragma unroll
            for (int k = 0; k < 16; ++k) { S[k] = D[k]; ld[t * 16 + k] = S[k]; }
        }
        __syncthreads();
    }
#pragma unroll
    for (int k = 0; k < 16; ++k) binc[t * 16 + k] = S[k];
}

__device__ __forceinline__ void load_gains(int s, int sc, const float* k1a,
                                           const float* k2a, float k1s, float k2s,
                                           float& g1, float& g2) {
    int si = (s < sc) ? s : 0;
    float a = k1a[si], b = k2a[si];
    g1 = (s < sc) ? a : k1s;
    g2 = (s < sc) ? b : k2s;
}

// K3: per-(chunk,coord) replay, j-fastest mapping (proven rounds 12/13).
__global__ __launch_bounds__(256) void k_emit(
    const float* __restrict__ meas, const float* __restrict__ ws_f,
    const int* __restrict__ ws_i, const float* __restrict__ lp,
    const float* __restrict__ binc, float* __restrict__ out) {
    int g = blockIdx.x * 256 + threadIdx.x;
    if (g >= NCJ) return;
    int c = g / 6;
    int j = g - 6 * c;
    int b = c / CPB, cl = c & (CPB - 1);
    float* est  = out;
    float* pred = out + T_LEN * 6;
    float* vel  = out + T_LEN * 12;
    if (c == 0) {
        float m0 = meas[j], m1 = meas[6 + j];
        est[j] = m0; est[6 + j] = m1;
        pred[j] = m0; pred[6 + j] = m1;
        vel[j] = m1 - m0;
    }
    // z1 then apply block prefix then local prefix
    float zx = meas[6 + j], zy = meas[j];
    if (b > 0) {
        const float* B = binc + (b - 1) * 16;
        float nx = B[0] * zx + B[1] * zy + B[4 + j];
        float ny = B[2] * zx + B[3] * zy + B[10 + j];
        zx = nx; zy = ny;
    }
    if (cl > 0) {
        const float* L = lp + (c - 1) * 16;
        float nx = L[0] * zx + L[1] * zy + L[4 + j];
        float ny = L[2] * zx + L[3] * zy + L[10 + j];
        zx = nx; zy = ny;
    }
    float x = zx, y = zy;
    int sc = ws_i[0];
    float k1s = ws_f[OFF_STEADY / 4], k2s = ws_f[OFF_STEADY / 4 + 1];
    const float* k1a = ws_f + OFF_K1 / 4;
    const float* k2a = ws_f + OFF_K2 / 4;
    int s0 = c * CHUNK;
#pragma unroll
    for (int i = 0; i < CHUNK; ++i) {
        int s = s0 + i;
        if (s < NSTEPS) {
            float g1, g2;
            load_gains(s, sc, k1a, k2a, k1s, k2s, g1, g2);
            float mj  = meas[(s + 2) * 6 + j];
            float vx  = x - y;
            float p   = x + vx;
            float inn = mj - p;
            float xn  = p + g1 * inn;
            float yn  = x + g2 * inn;
            est[(s + 2) * 6 + j]  = xn;
            pred[(s + 2) * 6 + j] = p;
            if (s < NSTEPS - 1) vel[(s + 1) * 6 + j] = xn - yn;
            x = xn; y = yn;
        }
    }
}

extern "C" void kernel_launch(void* const* d_in, const int* in_sizes, int n_in,
                              void* d_out, int out_size, void* d_ws, size_t ws_size,
                              hipStream_t stream) {
    const float* meas = (const float*)d_in[0];
    const float* pnc  = (const float*)d_in[1];
    const float* mnc  = (const float*)d_in[2];
    const float* cov  = (const float*)d_in[3];
    float* ws_f = (float*)d_ws;
    int*   ws_i = (int*)d_ws;
    float* lp   = ws_f + OFF_LP / 4;
    float* btot = ws_f + OFF_BT / 4;
    float* binc = ws_f + OFF_BI / 4;
    float* out  = (float*)d_out;

    k_chunk_scan<<<NBLK, K2T, 0, stream>>>(meas, pnc, mnc, cov, ws_f, ws_i, lp, btot);
    k_bscan<<<1, NBLK, 0, stream>>>(btot, binc);
    k_emit<<<NCJ / 256, 256, 0, stream>>>(meas, ws_f, ws_i, lp, binc, out);
}